// Round 5
// baseline (5931.945 us; speedup 1.0000x reference)
//
#include <hip/hip_runtime.h>
#include <cmath>

// out = (log(|DCT2(x)| + 1e-13) - mean) / std,  x: [384][256][256] f32.
// CORRECTNESS CONTRACT (R1-R3 evidence): reference accumulates in f32;
// near-zero DCT coefficients are f32 rounding NOISE and log() demands we
// reproduce that noise ~exactly. Every output element must be a single
// sequential fmaf chain, i ascending (stage 1) / j ascending (stage 2),
// with the stage-1 result rounded to f32. NO MFMA, NO split accumulators.
//
// R9 (from R8 counters: WRITE_SIZE 2.5GB = scratch spill; VGPR 64):
//  - R8's float[16] arrays written via float4-punning defeated SROA ->
//    alloca in scratch -> 25x write amplification. This version uses ONLY
//    named float4 / statically-indexed float4 arrays. No float[] punning.
//  - R8's second flaw: X and basis shared the in-order vmcnt counter, so
//    basis waits inherited X's HBM latency. Split the counters:
//      X:     per-lane float4 VMEM stream, named vA/vB ping-pong, dist 2
//             (wall slack ~1024cy @4 waves/SIMD >= 900cy HBM)  [vmcnt]
//      basis: LDS-staged 32-row double-buffered chunks (16KB/block),
//             4x uniform ds_read_b128 per row (broadcast, conflict-free),
//             named pA*/pB* ping-pong, dist 1 (~128cy >= 120cy ds lat)
//             [lgkmcnt, fine-grained -- unlike SMEM's lgkmcnt(0) drain
//             that caused R6/R7's 50% stall]
//    Staging loads issue at chunk TOP into regs, ds_write at chunk END
//    (latency hidden under 30 rows of FMA); 9 barriers total.
// Numerics: identical 256-step ascending fmaf chains, f32 intermediate,
// same epilogue as the passing R6/R7/R8 kernels (absmax 0.0078125).

#define HN    256
#define NIMG  384

// ---- f32 basis: Tdf[i][k] = (float)( cos(pi*(2i+1)*k/512) * s(k) ) --------
__global__ void basis_init(float* __restrict__ Tdf) {
    int idx = blockIdx.x * 256 + threadIdx.x;   // 65536
    int i = idx >> 8, k = idx & 255;
    double c = cos(M_PI * (2.0 * i + 1.0) * (double)k / 512.0);
    double s = (k == 0) ? sqrt(1.0 / 256.0) : sqrt(2.0 / 256.0);
    Tdf[idx] = (float)(c * s);
}

// blockIdx swizzle: the 4 blocks of one image land on the same XCD.
// n in [0,1536): img = (n&7)*48 + (n>>5), kg = (n>>3)&3. Bijective.
__device__ __forceinline__ void decode_bx(int n, int& img, int& kg) {
    img = (n & 7) * 48 + (n >> 5);
    kg  = (n >> 3) & 3;
}

#define FMAQ(Q, S, V) \
    acc[Q].x = fmaf((S), (V).x, acc[Q].x); \
    acc[Q].y = fmaf((S), (V).y, acc[Q].y); \
    acc[Q].z = fmaf((S), (V).z, acc[Q].z); \
    acc[Q].w = fmaf((S), (V).w, acc[Q].w);

#define FMAROW4(P0, P1, P2, P3, V) \
    FMAQ( 0, (P0).x, (V)) FMAQ( 1, (P0).y, (V)) FMAQ( 2, (P0).z, (V)) FMAQ( 3, (P0).w, (V)) \
    FMAQ( 4, (P1).x, (V)) FMAQ( 5, (P1).y, (V)) FMAQ( 6, (P1).z, (V)) FMAQ( 7, (P1).w, (V)) \
    FMAQ( 8, (P2).x, (V)) FMAQ( 9, (P2).y, (V)) FMAQ(10, (P2).z, (V)) FMAQ(11, (P2).w, (V)) \
    FMAQ(12, (P3).x, (V)) FMAQ(13, (P3).y, (V)) FMAQ(14, (P3).z, (V)) FMAQ(15, (P3).w, (V))

// Core: acc[q](.r) = sum_row Bas[row][k0+q] * V[row][4*lane+r], row ascending.
// Vb = per-lane vector-stream base (+4*lane, row stride HN).
// Basis slab [256][kg*64 .. +64) staged through 2x 32-row LDS chunks.
__device__ __forceinline__ void dct_core(
    const float* __restrict__ Vb, const float* __restrict__ Tdf,
    const int kg, const int wave, const int lane, float4 (&acc)[16])
{
    __shared__ float Bs[2][32][64];          // 16 KB
    const int sr = lane >> 4;                // staging: row-within-4
    const int sc = (lane & 15) << 2;         // staging: col
    const int r0 = 8 * wave + sr;            // staging row A (chunk-rel)
    const float* __restrict__ sb = Tdf + kg * 64 + sc;

    #pragma unroll
    for (int q = 0; q < 16; ++q) acc[q] = make_float4(0.f, 0.f, 0.f, 0.f);

    // prologue: stage chunk 0, prime X rows 0,1
    {
        float4 g0 = *(const float4*)(sb + r0 * HN);
        float4 g1 = *(const float4*)(sb + (r0 + 4) * HN);
        *(float4*)&Bs[0][r0][sc]     = g0;
        *(float4*)&Bs[0][r0 + 4][sc] = g1;
    }
    const float* __restrict__ vp = Vb;
    float4 vA = *(const float4*)vp; vp += HN;
    float4 vB = *(const float4*)vp; vp += HN;     // vp -> row 2
    __syncthreads();

    #pragma unroll 1
    for (int c = 0; c < 8; ++c) {
        const int buf = c & 1;
        // issue next chunk's staging loads now; ds_write at chunk end
        float4 h0, h1;
        if (c < 7) {
            const float* s2 = sb + ((c + 1) * 32 + r0) * HN;
            h0 = *(const float4*)s2;
            h1 = *(const float4*)(s2 + 4 * HN);
        }
        // prime basis rows 0,1 of this chunk (uniform ds_read -> broadcast)
        const float* __restrict__ pr = &Bs[buf][0][16 * wave];
        float4 pA0 = *(const float4*)(pr +  0);
        float4 pA1 = *(const float4*)(pr +  4);
        float4 pA2 = *(const float4*)(pr +  8);
        float4 pA3 = *(const float4*)(pr + 12);
        float4 pB0 = *(const float4*)(pr + 64);
        float4 pB1 = *(const float4*)(pr + 68);
        float4 pB2 = *(const float4*)(pr + 72);
        float4 pB3 = *(const float4*)(pr + 76);
        pr += 128;
        #pragma unroll 1
        for (int rr = 0; rr < 30; rr += 2) {
            FMAROW4(pA0, pA1, pA2, pA3, vA);           // row rr
            vA = *(const float4*)vp; vp += HN;         // X row +2 ahead
            pA0 = *(const float4*)(pr +  0);           // basis row rr+2
            pA1 = *(const float4*)(pr +  4);
            pA2 = *(const float4*)(pr +  8);
            pA3 = *(const float4*)(pr + 12);
            FMAROW4(pB0, pB1, pB2, pB3, vB);           // row rr+1
            vB = *(const float4*)vp; vp += HN;
            pB0 = *(const float4*)(pr + 64);           // basis row rr+3
            pB1 = *(const float4*)(pr + 68);
            pB2 = *(const float4*)(pr + 72);
            pB3 = *(const float4*)(pr + 76);
            pr += 128;
        }
        FMAROW4(pA0, pA1, pA2, pA3, vA);               // row 30
        if (c < 7) { vA = *(const float4*)vp; vp += HN; }
        FMAROW4(pB0, pB1, pB2, pB3, vB);               // row 31
        if (c < 7) { vB = *(const float4*)vp; vp += HN; }
        if (c < 7) {                                   // land next chunk
            *(float4*)&Bs[buf ^ 1][r0][sc]     = h0;
            *(float4*)&Bs[buf ^ 1][r0 + 4][sc] = h1;
        }
        __syncthreads();
    }
}

// ======================= two-kernel path ===================================
// Stage 1: T1t[img][j][k1] = sum_i Tdf[i][k1] * X[img][i][j]   (i ascending)
__global__ __launch_bounds__(256, 4) void t1_kernel(
    const float* __restrict__ X, const float* __restrict__ Tdf,
    float* __restrict__ T1t)
{
    int img, kg; decode_bx(blockIdx.x, img, kg);
    const int wave = threadIdx.x >> 6;
    const int lane = threadIdx.x & 63;
    const int k1b  = kg * 64 + 16 * wave;

    float4 acc[16];
    dct_core(X + (size_t)img * (HN * HN) + 4 * lane, Tdf, kg, wave, lane, acc);

    // transposed store: T1t[img][4*lane+r][k1b + 4a + 0..3]  (f32, np-equal)
    float* __restrict__ T1o =
        T1t + (size_t)img * (HN * HN) + (size_t)(4 * lane) * HN + k1b;
    const float* af = (const float*)acc;     // af[4*q + r]
    #pragma unroll
    for (int r = 0; r < 4; ++r)
        #pragma unroll
        for (int a = 0; a < 4; ++a) {
            float4 v = make_float4(af[4 * (4 * a + 0) + r],
                                   af[4 * (4 * a + 1) + r],
                                   af[4 * (4 * a + 2) + r],
                                   af[4 * (4 * a + 3) + r]);
            *(float4*)(T1o + r * HN + 4 * a) = v;
        }
}

// Stage 2: out[k1][k2] = sum_j T1t[j][k1] * Tdf[j][k2]   (j ascending) + epi
__global__ __launch_bounds__(256, 4) void y_kernel(
    const float* __restrict__ T1t, const float* __restrict__ Tdf,
    const float* __restrict__ meanp, const float* __restrict__ stdp,
    float* __restrict__ out)
{
    int img, kg; decode_bx(blockIdx.x, img, kg);
    const int wave = threadIdx.x >> 6;
    const int lane = threadIdx.x & 63;
    const int k2b  = kg * 64 + 16 * wave;

    float4 acc[16];
    dct_core(T1t + (size_t)img * (HN * HN) + 4 * lane, Tdf, kg, wave, lane, acc);

    // epilogue + transposed store: out[img][4*lane+r][k2b + 4a + 0..3]
    const float mean = meanp[0];
    const float stdv = stdp[0];
    float* __restrict__ O =
        out + (size_t)img * (HN * HN) + (size_t)(4 * lane) * HN + k2b;
    const float* af = (const float*)acc;     // af[4*q + r]
    #pragma unroll
    for (int r = 0; r < 4; ++r)
        #pragma unroll
        for (int a = 0; a < 4; ++a) {
            float4 v;
            v.x = (logf(fabsf(af[4 * (4 * a + 0) + r]) + 1e-13f) - mean) / stdv;
            v.y = (logf(fabsf(af[4 * (4 * a + 1) + r]) + 1e-13f) - mean) / stdv;
            v.z = (logf(fabsf(af[4 * (4 * a + 2) + r]) + 1e-13f) - mean) / stdv;
            v.w = (logf(fabsf(af[4 * (4 * a + 3) + r]) + 1e-13f) - mean) / stdv;
            *(float4*)(O + r * HN + 4 * a) = v;
        }
}

// ======================= fused fallback (R3, proven) =======================
#define SLAB 32
__global__ __launch_bounds__(256, 3) void dct2_f32(
    const float* __restrict__ X, const float* __restrict__ Tdf,
    const float* __restrict__ meanp, const float* __restrict__ stdp,
    float* __restrict__ out)
{
    __shared__ union SU {
        struct { float Xs[8][HN]; float CHc[8][SLAB]; } p1;
        float Bc[16][HN];
    } u;
    __shared__ float T1s[SLAB][HN + 1];

    const int t   = threadIdx.x;
    const int img = blockIdx.x >> 3;
    const int k0  = (blockIdx.x & 7) * SLAB;
    const float* __restrict__ Xi = X + (size_t)img * (HN * HN);
    const int ci = t & 7;
    const int ib = t >> 3;

    float acc[8][4];
    #pragma unroll
    for (int q = 0; q < 8; ++q)
        #pragma unroll
        for (int r = 0; r < 4; ++r) acc[q][r] = 0.0f;

    for (int i0 = 0; i0 < HN; i0 += 8) {
        {
            int rr = t >> 5, cc = (t & 31) * 4;
            float4 a = *(const float4*)(Xi + (i0 + rr) * HN + cc);
            float4 b = *(const float4*)(Xi + (i0 + rr) * HN + cc + 128);
            *(float4*)&u.p1.Xs[rr][cc]       = a;
            *(float4*)&u.p1.Xs[rr][cc + 128] = b;
            u.p1.CHc[rr][t & 31] = Tdf[(i0 + rr) * HN + k0 + (t & 31)];
        }
        __syncthreads();
        #pragma unroll
        for (int ii = 0; ii < 8; ++ii) {
            float xr[8];
            *(float4*)&xr[0] = *(const float4*)&u.p1.Xs[ii][8 * ib];
            *(float4*)&xr[4] = *(const float4*)&u.p1.Xs[ii][8 * ib + 4];
            float ch[4];
            *(float4*)&ch[0] = *(const float4*)&u.p1.CHc[ii][4 * ci];
            #pragma unroll
            for (int q = 0; q < 8; ++q)
                #pragma unroll
                for (int r = 0; r < 4; ++r)
                    acc[q][r] = fmaf(ch[r], xr[q], acc[q][r]);
        }
        __syncthreads();
    }
    #pragma unroll
    for (int q = 0; q < 8; ++q)
        #pragma unroll
        for (int r = 0; r < 4; ++r)
            T1s[4 * ci + r][8 * ib + q] = acc[q][r];
    __syncthreads();

    float acc2[8][4];
    #pragma unroll
    for (int q = 0; q < 8; ++q)
        #pragma unroll
        for (int r = 0; r < 4; ++r) acc2[q][r] = 0.0f;

    for (int j0 = 0; j0 < HN; j0 += 16) {
        #pragma unroll
        for (int rep = 0; rep < 4; ++rep) {
            int idx = rep * 1024 + t * 4;
            int p = idx >> 8, c = idx & 255;
            *(float4*)&u.Bc[p][c] = *(const float4*)(Tdf + (j0 + p) * HN + c);
        }
        __syncthreads();
        #pragma unroll
        for (int p = 0; p < 16; ++p) {
            float a[4];
            #pragma unroll
            for (int r = 0; r < 4; ++r) a[r] = T1s[4 * ci + r][j0 + p];
            float b[8];
            *(float4*)&b[0] = *(const float4*)&u.Bc[p][8 * ib];
            *(float4*)&b[4] = *(const float4*)&u.Bc[p][8 * ib + 4];
            #pragma unroll
            for (int q = 0; q < 8; ++q)
                #pragma unroll
                for (int r = 0; r < 4; ++r)
                    acc2[q][r] = fmaf(a[r], b[q], acc2[q][r]);
        }
        __syncthreads();
    }

    const float mean = meanp[0];
    const float stdv = stdp[0];
    #pragma unroll
    for (int q = 0; q < 8; ++q)
        #pragma unroll
        for (int r = 0; r < 4; ++r) {
            float v = (logf(fabsf(acc2[q][r]) + 1e-13f) - mean) / stdv;
            T1s[4 * ci + r][8 * ib + q] = v;
        }
    __syncthreads();

    float* __restrict__ O = out + (size_t)img * (HN * HN) + (size_t)k0 * HN;
    #pragma unroll
    for (int rep = 0; rep < 8; ++rep) {
        int idx = rep * 1024 + t * 4;
        int row = idx >> 8, col = idx & 255;
        float4 v = make_float4(T1s[row][col], T1s[row][col + 1],
                               T1s[row][col + 2], T1s[row][col + 3]);
        *(float4*)(O + row * HN + col) = v;
    }
}

extern "C" void kernel_launch(void* const* d_in, const int* in_sizes, int n_in,
                              void* d_out, int out_size, void* d_ws, size_t ws_size,
                              hipStream_t stream) {
    const float* X     = (const float*)d_in[0];
    const float* meanp = (const float*)d_in[1];
    const float* stdp  = (const float*)d_in[2];

    float* Tdf = (float*)d_ws;                       // 256 KB basis
    const size_t T1_OFF    = 256 * 1024;
    const size_t T1_BYTES  = (size_t)NIMG * HN * HN * sizeof(float);  // 100.7MB

    basis_init<<<256, 256, 0, stream>>>(Tdf);

    if (ws_size >= T1_OFF + T1_BYTES) {
        float* T1 = (float*)((char*)d_ws + T1_OFF);
        t1_kernel<<<NIMG * 4, 256, 0, stream>>>(X, Tdf, T1);
        y_kernel <<<NIMG * 4, 256, 0, stream>>>(T1, Tdf, meanp, stdp,
                                                (float*)d_out);
    } else {
        dct2_f32<<<NIMG * 8, 256, 0, stream>>>(X, Tdf, meanp, stdp,
                                               (float*)d_out);
    }
}

// Round 6
// 5027.872 us; speedup vs baseline: 1.1798x; 1.1798x over previous
//
#include <hip/hip_runtime.h>
#include <cmath>

// out = (log(|DCT2(x)| + 1e-13) - mean) / std,  x: [384][256][256] f32.
// CORRECTNESS CONTRACT (R1-R3 evidence): reference accumulates in f32;
// near-zero DCT coefficients are f32 rounding NOISE and log() demands we
// reproduce that noise ~exactly. Every output element must be a single
// sequential fmaf chain, i ascending (stage 1) / j ascending (stage 2),
// with the stage-1 result rounded to f32. NO MFMA, NO split accumulators.
//
// R10 (from R8/R9 spills + R6/R7 50%-stall evidence):
//  - SPILL RULE (R8: WRITE 2.5GB, R9: 7.9GB): register arrays accessed
//    via casted float* or passed by reference -> scratch. This kernel
//    uses ONLY named float4 variables with static .xyzw access. No
//    arrays, no device-fn refs, no LDS, no punning. Transposes are done
//    by NAME in make_float4(...).
//  - STALL RULE (R6/R7: VALUBusy ~50%): SMEM (s_load) returns out-of-
//    order -> any consume forces lgkmcnt(0), draining loads issued only
//    ~128cy earlier vs ~250cy L2 latency. Fix: basis rows via uniform-
//    address VMEM float4 (in-order vmcnt -> fine-grained waits).
//  - Schedule (4-row unroll, #pragma unroll 1 outer): X stream named
//    vA..vD at distance 4 (own-cover ~450cy, x4 waves wall ~1500cy >=
//    900cy HBM); basis named bA0-3/bB0-3 ping-pong at distance 2
//    (~256cy >= ~250cy L2). ~120 VGPR -> honest 4 waves/SIMD.
// Numerics: identical 256-step ascending fmaf chains, f32 intermediate,
// same epilogue as all passing kernels (absmax 0.0078125).

#define HN    256
#define NIMG  384

// ---- f32 basis: Tdf[i][k] = (float)( cos(pi*(2i+1)*k/512) * s(k) ) --------
__global__ void basis_init(float* __restrict__ Tdf) {
    int idx = blockIdx.x * 256 + threadIdx.x;   // 65536
    int i = idx >> 8, k = idx & 255;
    double c = cos(M_PI * (2.0 * i + 1.0) * (double)k / 512.0);
    double s = (k == 0) ? sqrt(1.0 / 256.0) : sqrt(2.0 / 256.0);
    Tdf[idx] = (float)(c * s);
}

// blockIdx swizzle: the 4 blocks of one image land on the same XCD.
// n in [0,1536): img = (n&7)*48 + (n>>5), kg = (n>>3)&3. Bijective.
__device__ __forceinline__ void decode_bx(int n, int& img, int& kg) {
    img = (n & 7) * 48 + (n >> 5);
    kg  = (n >> 3) & 3;
}

// ---- named-register building blocks (NO arrays anywhere) ------------------
#define FMA4(Aq, S, V) \
    Aq.x = fmaf((S), (V).x, Aq.x); \
    Aq.y = fmaf((S), (V).y, Aq.y); \
    Aq.z = fmaf((S), (V).z, Aq.z); \
    Aq.w = fmaf((S), (V).w, Aq.w);

#define FMA_BLK(B0, B1, B2, B3, V) \
    FMA4(A0,  (B0).x, V) FMA4(A1,  (B0).y, V) FMA4(A2,  (B0).z, V) FMA4(A3,  (B0).w, V) \
    FMA4(A4,  (B1).x, V) FMA4(A5,  (B1).y, V) FMA4(A6,  (B1).z, V) FMA4(A7,  (B1).w, V) \
    FMA4(A8,  (B2).x, V) FMA4(A9,  (B2).y, V) FMA4(A10, (B2).z, V) FMA4(A11, (B2).w, V) \
    FMA4(A12, (B3).x, V) FMA4(A13, (B3).y, V) FMA4(A14, (B3).z, V) FMA4(A15, (B3).w, V)

#define LDB(B0, B1, B2, B3, P) \
    B0 = *(const float4*)((P) + 0); \
    B1 = *(const float4*)((P) + 4); \
    B2 = *(const float4*)((P) + 8); \
    B3 = *(const float4*)((P) + 12);

#define DECL_ACC \
    float4 A0  = make_float4(0.f,0.f,0.f,0.f), A1  = make_float4(0.f,0.f,0.f,0.f), \
           A2  = make_float4(0.f,0.f,0.f,0.f), A3  = make_float4(0.f,0.f,0.f,0.f), \
           A4  = make_float4(0.f,0.f,0.f,0.f), A5  = make_float4(0.f,0.f,0.f,0.f), \
           A6  = make_float4(0.f,0.f,0.f,0.f), A7  = make_float4(0.f,0.f,0.f,0.f), \
           A8  = make_float4(0.f,0.f,0.f,0.f), A9  = make_float4(0.f,0.f,0.f,0.f), \
           A10 = make_float4(0.f,0.f,0.f,0.f), A11 = make_float4(0.f,0.f,0.f,0.f), \
           A12 = make_float4(0.f,0.f,0.f,0.f), A13 = make_float4(0.f,0.f,0.f,0.f), \
           A14 = make_float4(0.f,0.f,0.f,0.f), A15 = make_float4(0.f,0.f,0.f,0.f);

// rows ascending; X at distance 4 (vA..vD), basis ping-pong distance 2.
#define DCT_BODY(VBASE, BBASE) \
    DECL_ACC \
    const float* vp = (VBASE); \
    const float* bp = (BBASE); \
    float4 vA = *(const float4*)(vp); \
    float4 vB = *(const float4*)(vp + HN); \
    float4 vC = *(const float4*)(vp + 2 * HN); \
    float4 vD = *(const float4*)(vp + 3 * HN); \
    vp += 4 * HN; \
    float4 bA0, bA1, bA2, bA3, bB0, bB1, bB2, bB3; \
    LDB(bA0, bA1, bA2, bA3, bp); \
    LDB(bB0, bB1, bB2, bB3, bp + HN); \
    bp += 2 * HN; \
    _Pragma("unroll 1") \
    for (int i = 0; i < HN - 4; i += 4) { \
        FMA_BLK(bA0, bA1, bA2, bA3, vA);       /* row i   */ \
        vA = *(const float4*)(vp);             /* row i+4 */ \
        LDB(bA0, bA1, bA2, bA3, bp);           /* row i+2 */ \
        FMA_BLK(bB0, bB1, bB2, bB3, vB);       /* row i+1 */ \
        vB = *(const float4*)(vp + HN);        /* row i+5 */ \
        LDB(bB0, bB1, bB2, bB3, bp + HN);      /* row i+3 */ \
        FMA_BLK(bA0, bA1, bA2, bA3, vC);       /* row i+2 */ \
        vC = *(const float4*)(vp + 2 * HN);    /* row i+6 */ \
        LDB(bA0, bA1, bA2, bA3, bp + 2 * HN);  /* row i+4 */ \
        FMA_BLK(bB0, bB1, bB2, bB3, vD);       /* row i+3 */ \
        vD = *(const float4*)(vp + 3 * HN);    /* row i+7 */ \
        LDB(bB0, bB1, bB2, bB3, bp + 3 * HN);  /* row i+5 */ \
        vp += 4 * HN; bp += 4 * HN; \
    } \
    /* tail: vA..vD = rows 252..255; bA=252, bB=253; bp -> 254 */ \
    FMA_BLK(bA0, bA1, bA2, bA3, vA);           /* 252 */ \
    LDB(bA0, bA1, bA2, bA3, bp);               /* 254 */ \
    FMA_BLK(bB0, bB1, bB2, bB3, vB);           /* 253 */ \
    LDB(bB0, bB1, bB2, bB3, bp + HN);          /* 255 */ \
    FMA_BLK(bA0, bA1, bA2, bA3, vC);           /* 254 */ \
    FMA_BLK(bB0, bB1, bB2, bB3, vD);           /* 255 */

// ======================= two-kernel path ===================================
// Stage 1: T1t[img][j][k1] = sum_i Tdf[i][k1] * X[img][i][j]   (i ascending)
// Block = 4 waves; wave w owns k1 slab [k1b,k1b+16), lanes span j (4/lane).
// Vector: X row i (coalesced float4/lane). Basis: uniform-address VMEM.
__global__ __launch_bounds__(256, 4) void t1_kernel(
    const float* __restrict__ X, const float* __restrict__ Tdf,
    float* __restrict__ T1t)
{
    int img, kg; decode_bx(blockIdx.x, img, kg);
    const int wave = threadIdx.x >> 6;
    const int lane = threadIdx.x & 63;
    const int k1b  = kg * 64 + 16 * wave;

    DCT_BODY(X + (size_t)img * (HN * HN) + 4 * lane, Tdf + k1b)

    // transposed store BY NAME: T1t[img][4*lane+r][k1b + 0..15]
    float* __restrict__ T1o =
        T1t + (size_t)img * (HN * HN) + (size_t)(4 * lane) * HN + k1b;
    #define T1_ROW(PTR, C) \
        *(float4*)((PTR) + 0)  = make_float4(A0.C,  A1.C,  A2.C,  A3.C); \
        *(float4*)((PTR) + 4)  = make_float4(A4.C,  A5.C,  A6.C,  A7.C); \
        *(float4*)((PTR) + 8)  = make_float4(A8.C,  A9.C,  A10.C, A11.C); \
        *(float4*)((PTR) + 12) = make_float4(A12.C, A13.C, A14.C, A15.C);
    T1_ROW(T1o + 0 * HN, x)
    T1_ROW(T1o + 1 * HN, y)
    T1_ROW(T1o + 2 * HN, z)
    T1_ROW(T1o + 3 * HN, w)
    #undef T1_ROW
}

// Stage 2: out[k1][k2] = sum_j T1t[j][k1] * Tdf[j][k2]   (j ascending) + epi
// Vector: T1t row j (coalesced, L3-warm). Basis: uniform-address VMEM.
__global__ __launch_bounds__(256, 4) void y_kernel(
    const float* __restrict__ T1t, const float* __restrict__ Tdf,
    const float* __restrict__ meanp, const float* __restrict__ stdp,
    float* __restrict__ out)
{
    int img, kg; decode_bx(blockIdx.x, img, kg);
    const int wave = threadIdx.x >> 6;
    const int lane = threadIdx.x & 63;
    const int k2b  = kg * 64 + 16 * wave;

    DCT_BODY(T1t + (size_t)img * (HN * HN) + 4 * lane, Tdf + k2b)

    const float mean = meanp[0];
    const float stdv = stdp[0];
    float* __restrict__ O =
        out + (size_t)img * (HN * HN) + (size_t)(4 * lane) * HN + k2b;
    #define E(v) ((logf(fabsf(v) + 1e-13f) - mean) / stdv)
    #define Y_ROW(PTR, C) \
        *(float4*)((PTR) + 0)  = make_float4(E(A0.C),  E(A1.C),  E(A2.C),  E(A3.C)); \
        *(float4*)((PTR) + 4)  = make_float4(E(A4.C),  E(A5.C),  E(A6.C),  E(A7.C)); \
        *(float4*)((PTR) + 8)  = make_float4(E(A8.C),  E(A9.C),  E(A10.C), E(A11.C)); \
        *(float4*)((PTR) + 12) = make_float4(E(A12.C), E(A13.C), E(A14.C), E(A15.C));
    Y_ROW(O + 0 * HN, x)
    Y_ROW(O + 1 * HN, y)
    Y_ROW(O + 2 * HN, z)
    Y_ROW(O + 3 * HN, w)
    #undef Y_ROW
    #undef E
}

// ======================= fused fallback (R3, proven) =======================
#define SLAB 32
__global__ __launch_bounds__(256, 3) void dct2_f32(
    const float* __restrict__ X, const float* __restrict__ Tdf,
    const float* __restrict__ meanp, const float* __restrict__ stdp,
    float* __restrict__ out)
{
    __shared__ union SU {
        struct { float Xs[8][HN]; float CHc[8][SLAB]; } p1;
        float Bc[16][HN];
    } u;
    __shared__ float T1s[SLAB][HN + 1];

    const int t   = threadIdx.x;
    const int img = blockIdx.x >> 3;
    const int k0  = (blockIdx.x & 7) * SLAB;
    const float* __restrict__ Xi = X + (size_t)img * (HN * HN);
    const int ci = t & 7;
    const int ib = t >> 3;

    float acc[8][4];
    #pragma unroll
    for (int q = 0; q < 8; ++q)
        #pragma unroll
        for (int r = 0; r < 4; ++r) acc[q][r] = 0.0f;

    for (int i0 = 0; i0 < HN; i0 += 8) {
        {
            int rr = t >> 5, cc = (t & 31) * 4;
            float4 a = *(const float4*)(Xi + (i0 + rr) * HN + cc);
            float4 b = *(const float4*)(Xi + (i0 + rr) * HN + cc + 128);
            *(float4*)&u.p1.Xs[rr][cc]       = a;
            *(float4*)&u.p1.Xs[rr][cc + 128] = b;
            u.p1.CHc[rr][t & 31] = Tdf[(i0 + rr) * HN + k0 + (t & 31)];
        }
        __syncthreads();
        #pragma unroll
        for (int ii = 0; ii < 8; ++ii) {
            float xr[8];
            *(float4*)&xr[0] = *(const float4*)&u.p1.Xs[ii][8 * ib];
            *(float4*)&xr[4] = *(const float4*)&u.p1.Xs[ii][8 * ib + 4];
            float ch[4];
            *(float4*)&ch[0] = *(const float4*)&u.p1.CHc[ii][4 * ci];
            #pragma unroll
            for (int q = 0; q < 8; ++q)
                #pragma unroll
                for (int r = 0; r < 4; ++r)
                    acc[q][r] = fmaf(ch[r], xr[q], acc[q][r]);
        }
        __syncthreads();
    }
    #pragma unroll
    for (int q = 0; q < 8; ++q)
        #pragma unroll
        for (int r = 0; r < 4; ++r)
            T1s[4 * ci + r][8 * ib + q] = acc[q][r];
    __syncthreads();

    float acc2[8][4];
    #pragma unroll
    for (int q = 0; q < 8; ++q)
        #pragma unroll
        for (int r = 0; r < 4; ++r) acc2[q][r] = 0.0f;

    for (int j0 = 0; j0 < HN; j0 += 16) {
        #pragma unroll
        for (int rep = 0; rep < 4; ++rep) {
            int idx = rep * 1024 + t * 4;
            int p = idx >> 8, c = idx & 255;
            *(float4*)&u.Bc[p][c] = *(const float4*)(Tdf + (j0 + p) * HN + c);
        }
        __syncthreads();
        #pragma unroll
        for (int p = 0; p < 16; ++p) {
            float a[4];
            #pragma unroll
            for (int r = 0; r < 4; ++r) a[r] = T1s[4 * ci + r][j0 + p];
            float b[8];
            *(float4*)&b[0] = *(const float4*)&u.Bc[p][8 * ib];
            *(float4*)&b[4] = *(const float4*)&u.Bc[p][8 * ib + 4];
            #pragma unroll
            for (int q = 0; q < 8; ++q)
                #pragma unroll
                for (int r = 0; r < 4; ++r)
                    acc2[q][r] = fmaf(a[r], b[q], acc2[q][r]);
        }
        __syncthreads();
    }

    const float mean = meanp[0];
    const float stdv = stdp[0];
    #pragma unroll
    for (int q = 0; q < 8; ++q)
        #pragma unroll
        for (int r = 0; r < 4; ++r) {
            float v = (logf(fabsf(acc2[q][r]) + 1e-13f) - mean) / stdv;
            T1s[4 * ci + r][8 * ib + q] = v;
        }
    __syncthreads();

    float* __restrict__ O = out + (size_t)img * (HN * HN) + (size_t)k0 * HN;
    #pragma unroll
    for (int rep = 0; rep < 8; ++rep) {
        int idx = rep * 1024 + t * 4;
        int row = idx >> 8, col = idx & 255;
        float4 v = make_float4(T1s[row][col], T1s[row][col + 1],
                               T1s[row][col + 2], T1s[row][col + 3]);
        *(float4*)(O + row * HN + col) = v;
    }
}

extern "C" void kernel_launch(void* const* d_in, const int* in_sizes, int n_in,
                              void* d_out, int out_size, void* d_ws, size_t ws_size,
                              hipStream_t stream) {
    const float* X     = (const float*)d_in[0];
    const float* meanp = (const float*)d_in[1];
    const float* stdp  = (const float*)d_in[2];

    float* Tdf = (float*)d_ws;                       // 256 KB basis
    const size_t T1_OFF    = 256 * 1024;
    const size_t T1_BYTES  = (size_t)NIMG * HN * HN * sizeof(float);  // 100.7MB

    basis_init<<<256, 256, 0, stream>>>(Tdf);

    if (ws_size >= T1_OFF + T1_BYTES) {
        float* T1 = (float*)((char*)d_ws + T1_OFF);
        t1_kernel<<<NIMG * 4, 256, 0, stream>>>(X, Tdf, T1);
        y_kernel <<<NIMG * 4, 256, 0, stream>>>(T1, Tdf, meanp, stdp,
                                                (float*)d_out);
    } else {
        dct2_f32<<<NIMG * 8, 256, 0, stream>>>(X, Tdf, meanp, stdp,
                                               (float*)d_out);
    }
}

// Round 7
// 519.266 us; speedup vs baseline: 11.4237x; 9.6826x over previous
//
#include <hip/hip_runtime.h>
#include <cmath>

// out = (log(|DCT2(x)| + 1e-13) - mean) / std,  x: [384][256][256] f32.
// CORRECTNESS CONTRACT (R1-R3 evidence): reference accumulates in f32;
// near-zero DCT coefficients are f32 rounding NOISE and log() demands we
// reproduce that noise ~exactly. Every output element must be a single
// sequential fmaf chain, i ascending (stage 1) / j ascending (stage 2),
// with the stage-1 result rounded to f32. NO MFMA, NO split accumulators.
//
// R11. Register-envelope synthesis of R6-R10:
//  - gfx950 gives this kernel ~64 arch VGPRs; the float4 acc[16] lives in
//    AGPRs ONLY in the R6 pattern (plain array, statically unrolled
//    indexing, no by-ref, cast-to-float* only in the epilogue). R8/R10
//    spilled because a persistent 32-VGPR basis buffer + X buffers blew
//    the ~64-VGPR envelope; R9 spilled via by-ref acc (un-AGPR-able).
//  - R6/R7's 50% stall: SMEM returns out-of-order -> lgkmcnt(0) full
//    drain before every FMA block. Fix WITHOUT a VGPR buffer: basis goes
//    through LDS ([128][64] half-slab, 32KB, staged twice, 3 barriers).
//    ds_read gets fine-grained in-order lgkmcnt(N) waits (m97), and the
//    b0..b3/c0..c3 temporaries die immediately after each row's FMAs.
//    Reads are wave-uniform -> broadcast, zero bank conflicts.
//  - X stream: named vA/vB depth-2 (R7-proven safe), wall cover at
//    4 waves/SIMD ~1000cy >= 900cy HBM.
//  Budget: ~50 arch VGPR + 64 AGPR acc = 114 <= 128 @ 4 waves/SIMD.
// Numerics: identical 256-step ascending fmaf chains, f32 intermediate,
// same epilogue as all passing kernels (absmax 0.0078125).

#define HN    256
#define NIMG  384

// ---- f32 basis: Tdf[i][k] = (float)( cos(pi*(2i+1)*k/512) * s(k) ) --------
__global__ void basis_init(float* __restrict__ Tdf) {
    int idx = blockIdx.x * 256 + threadIdx.x;   // 65536
    int i = idx >> 8, k = idx & 255;
    double c = cos(M_PI * (2.0 * i + 1.0) * (double)k / 512.0);
    double s = (k == 0) ? sqrt(1.0 / 256.0) : sqrt(2.0 / 256.0);
    Tdf[idx] = (float)(c * s);
}

// blockIdx swizzle: the 4 blocks of one image land on the same XCD.
// n in [0,1536): img = (n&7)*48 + (n>>5), kg = (n>>3)&3. Bijective.
__device__ __forceinline__ void decode_bx(int n, int& img, int& kg) {
    img = (n & 7) * 48 + (n >> 5);
    kg  = (n >> 3) & 3;
}

// ---- FMA building blocks: acc[16] statically indexed (R6 AGPR pattern) ----
#define FMAQ(Q, S, V) \
    acc[Q].x = fmaf((S), (V).x, acc[Q].x); \
    acc[Q].y = fmaf((S), (V).y, acc[Q].y); \
    acc[Q].z = fmaf((S), (V).z, acc[Q].z); \
    acc[Q].w = fmaf((S), (V).w, acc[Q].w);

#define FMAROW(B0, B1, B2, B3, V) \
    FMAQ( 0, (B0).x, V) FMAQ( 1, (B0).y, V) FMAQ( 2, (B0).z, V) FMAQ( 3, (B0).w, V) \
    FMAQ( 4, (B1).x, V) FMAQ( 5, (B1).y, V) FMAQ( 6, (B1).z, V) FMAQ( 7, (B1).w, V) \
    FMAQ( 8, (B2).x, V) FMAQ( 9, (B2).y, V) FMAQ(10, (B2).z, V) FMAQ(11, (B2).w, V) \
    FMAQ(12, (B3).x, V) FMAQ(13, (B3).y, V) FMAQ(14, (B3).z, V) FMAQ(15, (B3).w, V)

// stage half H of the basis slab: rows [H*128, H*128+128), cols [kg*64,+64)
// thread t writes 8 float4; consecutive t -> consecutive 16B (conflict-free).
#define STAGE(H) \
    _Pragma("unroll") \
    for (int rep = 0; rep < 8; ++rep) { \
        int f = rep * 256 + (int)threadIdx.x; \
        int row = f >> 4, c4 = (f & 15) << 2; \
        *(float4*)&Bs[row][c4] = \
            *(const float4*)(Tdf + (size_t)((H) * 128 + row) * HN + kg * 64 + c4); \
    }

// two rows: consume vA (row BR of current half) and vB (row BR+1); basis via
// wave-uniform ds_read_b128 temporaries (die immediately -> no VGPR buffer).
#define BODY2(BR, XLOADS) { \
    float4 b0 = *(const float4*)&Bs[BR][co +  0]; \
    float4 b1 = *(const float4*)&Bs[BR][co +  4]; \
    float4 b2 = *(const float4*)&Bs[BR][co +  8]; \
    float4 b3 = *(const float4*)&Bs[BR][co + 12]; \
    FMAROW(b0, b1, b2, b3, vA) \
    if (XLOADS) { vA = *(const float4*)vp; vp += HN; } \
    float4 c0 = *(const float4*)&Bs[(BR) + 1][co +  0]; \
    float4 c1 = *(const float4*)&Bs[(BR) + 1][co +  4]; \
    float4 c2 = *(const float4*)&Bs[(BR) + 1][co +  8]; \
    float4 c3 = *(const float4*)&Bs[(BR) + 1][co + 12]; \
    FMAROW(c0, c1, c2, c3, vB) \
    if (XLOADS) { vB = *(const float4*)vp; vp += HN; } }

// full 256-row accumulation, rows ascending. Declares Bs, acc, co.
#define DCT_CORE(VBASE) \
    __shared__ float Bs[128][64]; \
    const int co = 16 * ((int)threadIdx.x >> 6); \
    float4 acc[16]; \
    _Pragma("unroll") \
    for (int q = 0; q < 16; ++q) acc[q] = make_float4(0.f, 0.f, 0.f, 0.f); \
    const float* vp = (VBASE); \
    float4 vA = *(const float4*)vp; vp += HN; \
    float4 vB = *(const float4*)vp; vp += HN; \
    STAGE(0) \
    __syncthreads(); \
    _Pragma("unroll 1") \
    for (int rr = 0; rr < 128; rr += 2) { BODY2(rr, 1) }   /* rows 0..127   */ \
    __syncthreads(); \
    STAGE(1) \
    __syncthreads(); \
    _Pragma("unroll 1") \
    for (int rr = 0; rr < 124; rr += 2) { BODY2(rr, 1) }   /* rows 128..251 */ \
    BODY2(124, 1)                                          /* rows 252..253 */ \
    BODY2(126, 0)                                          /* rows 254..255 */

// ======================= two-kernel path ===================================
// Stage 1: T1t[img][j][k1] = sum_i Tdf[i][k1] * X[img][i][j]   (i ascending)
// Block = 4 waves; wave w owns k1 slab [k1b,k1b+16), lanes span j (4/lane).
__global__ __launch_bounds__(256, 4) void t1_kernel(
    const float* __restrict__ X, const float* __restrict__ Tdf,
    float* __restrict__ T1t)
{
    int img, kg; decode_bx(blockIdx.x, img, kg);
    const int lane = threadIdx.x & 63;

    DCT_CORE(X + (size_t)img * (HN * HN) + 4 * lane)

    // transposed store (R6-proven epilogue): T1t[img][4*lane+r][k1b+4a+0..3]
    const int k1b = kg * 64 + co;
    float* __restrict__ T1o =
        T1t + (size_t)img * (HN * HN) + (size_t)(4 * lane) * HN + k1b;
    const float* af = (const float*)acc;     // af[4*q + r]
    #pragma unroll
    for (int r = 0; r < 4; ++r)
        #pragma unroll
        for (int a = 0; a < 4; ++a) {
            float4 v = make_float4(af[4 * (4 * a + 0) + r],
                                   af[4 * (4 * a + 1) + r],
                                   af[4 * (4 * a + 2) + r],
                                   af[4 * (4 * a + 3) + r]);
            *(float4*)(T1o + r * HN + 4 * a) = v;
        }
}

// Stage 2: out[k1][k2] = sum_j T1t[j][k1] * Tdf[j][k2]   (j ascending) + epi
// Vector stream: T1t rows (coalesced, L3-warm). Basis: same LDS staging.
__global__ __launch_bounds__(256, 4) void y_kernel(
    const float* __restrict__ T1t, const float* __restrict__ Tdf,
    const float* __restrict__ meanp, const float* __restrict__ stdp,
    float* __restrict__ out)
{
    int img, kg; decode_bx(blockIdx.x, img, kg);
    const int lane = threadIdx.x & 63;

    DCT_CORE(T1t + (size_t)img * (HN * HN) + 4 * lane)

    const float mean = meanp[0];
    const float stdv = stdp[0];
    const int k2b = kg * 64 + co;
    float* __restrict__ O =
        out + (size_t)img * (HN * HN) + (size_t)(4 * lane) * HN + k2b;
    const float* af = (const float*)acc;     // af[4*q + r]
    #pragma unroll
    for (int r = 0; r < 4; ++r)
        #pragma unroll
        for (int a = 0; a < 4; ++a) {
            float4 v;
            v.x = (logf(fabsf(af[4 * (4 * a + 0) + r]) + 1e-13f) - mean) / stdv;
            v.y = (logf(fabsf(af[4 * (4 * a + 1) + r]) + 1e-13f) - mean) / stdv;
            v.z = (logf(fabsf(af[4 * (4 * a + 2) + r]) + 1e-13f) - mean) / stdv;
            v.w = (logf(fabsf(af[4 * (4 * a + 3) + r]) + 1e-13f) - mean) / stdv;
            *(float4*)(O + r * HN + 4 * a) = v;
        }
}

// ======================= fused fallback (R3, proven) =======================
#define SLAB 32
__global__ __launch_bounds__(256, 3) void dct2_f32(
    const float* __restrict__ X, const float* __restrict__ Tdf,
    const float* __restrict__ meanp, const float* __restrict__ stdp,
    float* __restrict__ out)
{
    __shared__ union SU {
        struct { float Xs[8][HN]; float CHc[8][SLAB]; } p1;
        float Bc[16][HN];
    } u;
    __shared__ float T1s[SLAB][HN + 1];

    const int t   = threadIdx.x;
    const int img = blockIdx.x >> 3;
    const int k0  = (blockIdx.x & 7) * SLAB;
    const float* __restrict__ Xi = X + (size_t)img * (HN * HN);
    const int ci = t & 7;
    const int ib = t >> 3;

    float acc[8][4];
    #pragma unroll
    for (int q = 0; q < 8; ++q)
        #pragma unroll
        for (int r = 0; r < 4; ++r) acc[q][r] = 0.0f;

    for (int i0 = 0; i0 < HN; i0 += 8) {
        {
            int rr = t >> 5, cc = (t & 31) * 4;
            float4 a = *(const float4*)(Xi + (i0 + rr) * HN + cc);
            float4 b = *(const float4*)(Xi + (i0 + rr) * HN + cc + 128);
            *(float4*)&u.p1.Xs[rr][cc]       = a;
            *(float4*)&u.p1.Xs[rr][cc + 128] = b;
            u.p1.CHc[rr][t & 31] = Tdf[(i0 + rr) * HN + k0 + (t & 31)];
        }
        __syncthreads();
        #pragma unroll
        for (int ii = 0; ii < 8; ++ii) {
            float xr[8];
            *(float4*)&xr[0] = *(const float4*)&u.p1.Xs[ii][8 * ib];
            *(float4*)&xr[4] = *(const float4*)&u.p1.Xs[ii][8 * ib + 4];
            float ch[4];
            *(float4*)&ch[0] = *(const float4*)&u.p1.CHc[ii][4 * ci];
            #pragma unroll
            for (int q = 0; q < 8; ++q)
                #pragma unroll
                for (int r = 0; r < 4; ++r)
                    acc[q][r] = fmaf(ch[r], xr[q], acc[q][r]);
        }
        __syncthreads();
    }
    #pragma unroll
    for (int q = 0; q < 8; ++q)
        #pragma unroll
        for (int r = 0; r < 4; ++r)
            T1s[4 * ci + r][8 * ib + q] = acc[q][r];
    __syncthreads();

    float acc2[8][4];
    #pragma unroll
    for (int q = 0; q < 8; ++q)
        #pragma unroll
        for (int r = 0; r < 4; ++r) acc2[q][r] = 0.0f;

    for (int j0 = 0; j0 < HN; j0 += 16) {
        #pragma unroll
        for (int rep = 0; rep < 4; ++rep) {
            int idx = rep * 1024 + t * 4;
            int p = idx >> 8, c = idx & 255;
            *(float4*)&u.Bc[p][c] = *(const float4*)(Tdf + (j0 + p) * HN + c);
        }
        __syncthreads();
        #pragma unroll
        for (int p = 0; p < 16; ++p) {
            float a[4];
            #pragma unroll
            for (int r = 0; r < 4; ++r) a[r] = T1s[4 * ci + r][j0 + p];
            float b[8];
            *(float4*)&b[0] = *(const float4*)&u.Bc[p][8 * ib];
            *(float4*)&b[4] = *(const float4*)&u.Bc[p][8 * ib + 4];
            #pragma unroll
            for (int q = 0; q < 8; ++q)
                #pragma unroll
                for (int r = 0; r < 4; ++r)
                    acc2[q][r] = fmaf(a[r], b[q], acc2[q][r]);
        }
        __syncthreads();
    }

    const float mean = meanp[0];
    const float stdv = stdp[0];
    #pragma unroll
    for (int q = 0; q < 8; ++q)
        #pragma unroll
        for (int r = 0; r < 4; ++r) {
            float v = (logf(fabsf(acc2[q][r]) + 1e-13f) - mean) / stdv;
            T1s[4 * ci + r][8 * ib + q] = v;
        }
    __syncthreads();

    float* __restrict__ O = out + (size_t)img * (HN * HN) + (size_t)k0 * HN;
    #pragma unroll
    for (int rep = 0; rep < 8; ++rep) {
        int idx = rep * 1024 + t * 4;
        int row = idx >> 8, col = idx & 255;
        float4 v = make_float4(T1s[row][col], T1s[row][col + 1],
                               T1s[row][col + 2], T1s[row][col + 3]);
        *(float4*)(O + row * HN + col) = v;
    }
}

extern "C" void kernel_launch(void* const* d_in, const int* in_sizes, int n_in,
                              void* d_out, int out_size, void* d_ws, size_t ws_size,
                              hipStream_t stream) {
    const float* X     = (const float*)d_in[0];
    const float* meanp = (const float*)d_in[1];
    const float* stdp  = (const float*)d_in[2];

    float* Tdf = (float*)d_ws;                       // 256 KB basis
    const size_t T1_OFF    = 256 * 1024;
    const size_t T1_BYTES  = (size_t)NIMG * HN * HN * sizeof(float);  // 100.7MB

    basis_init<<<256, 256, 0, stream>>>(Tdf);

    if (ws_size >= T1_OFF + T1_BYTES) {
        float* T1 = (float*)((char*)d_ws + T1_OFF);
        t1_kernel<<<NIMG * 4, 256, 0, stream>>>(X, Tdf, T1);
        y_kernel <<<NIMG * 4, 256, 0, stream>>>(T1, Tdf, meanp, stdp,
                                                (float*)d_out);
    } else {
        dct2_f32<<<NIMG * 8, 256, 0, stream>>>(X, Tdf, meanp, stdp,
                                               (float*)d_out);
    }
}